// Round 1
// baseline (10248.527 us; speedup 1.0000x reference)
//
#include <hip/hip_runtime.h>
#include <hip/hip_bf16.h>
#include <hip/hip_cooperative_groups.h>

namespace cg = cooperative_groups;

typedef __bf16 bf16x8 __attribute__((ext_vector_type(8)));
typedef float f32x4 __attribute__((ext_vector_type(4)));

#define TSTEPS 256
#define NB 64
#define ID 1024
#define HD 1024
#define KD 2048
#define NGATE 4096

// ws layout (bytes)
#define XOFF 0ull
#define WOFF 33554432ull
#define VOFF 50331648ull
#define BOFF 52428800ull
#define HOFF 52445184ull

__device__ __forceinline__ unsigned short f2b(float f) {
    unsigned int u = __float_as_uint(f);
    unsigned int r = (u + 0x7fffu + ((u >> 16) & 1u)) >> 16;
    return (unsigned short)r;
}

__global__ void cvt_x(const float* __restrict__ in, unsigned short* __restrict__ out) {
    size_t i = ((size_t)blockIdx.x * blockDim.x + threadIdx.x) * 8;
    float4 a = *(const float4*)(in + i);
    float4 b = *(const float4*)(in + i + 4);
    union { unsigned short h[8]; uint4 u; } o;
    o.h[0] = f2b(a.x); o.h[1] = f2b(a.y); o.h[2] = f2b(a.z); o.h[3] = f2b(a.w);
    o.h[4] = f2b(b.x); o.h[5] = f2b(b.y); o.h[6] = f2b(b.z); o.h[7] = f2b(b.w);
    *(uint4*)(out + i) = o.u;
}

__global__ void cvt_w(const float* __restrict__ Wf, const float* __restrict__ Wi,
                      const float* __restrict__ Wo, const float* __restrict__ Wc,
                      const float* __restrict__ bf_, const float* __restrict__ bi_,
                      const float* __restrict__ bo_, const float* __restrict__ bc_,
                      unsigned short* __restrict__ Wr, float* __restrict__ bias_r) {
    int idx = blockIdx.x * 256 + threadIdx.x;   // 4096*256 total
    int np = idx >> 8;            // n' = hcol*4 + gate
    int k  = (idx & 255) * 8;
    int g = np & 3, h = np >> 2;
    const float* W = (g == 0) ? Wf : (g == 1) ? Wi : (g == 2) ? Wo : Wc;
    const float* src = W + (size_t)h * KD + k;
    float4 a = *(const float4*)src;
    float4 b = *(const float4*)(src + 4);
    union { unsigned short h[8]; uint4 u; } o;
    o.h[0] = f2b(a.x); o.h[1] = f2b(a.y); o.h[2] = f2b(a.z); o.h[3] = f2b(a.w);
    o.h[4] = f2b(b.x); o.h[5] = f2b(b.y); o.h[6] = f2b(b.z); o.h[7] = f2b(b.w);
    *(uint4*)(Wr + (size_t)np * KD + k) = o.u;
    if (k == 0) {
        const float* B = (g == 0) ? bf_ : (g == 1) ? bi_ : (g == 2) ? bo_ : bc_;
        bias_r[np] = B[h];
    }
}

__global__ void cvt_v(const float* __restrict__ V, unsigned short* __restrict__ out) {
    size_t i = ((size_t)blockIdx.x * blockDim.x + threadIdx.x) * 8;
    float4 a = *(const float4*)(V + i);
    float4 b = *(const float4*)(V + i + 4);
    union { unsigned short h[8]; uint4 u; } o;
    o.h[0] = f2b(a.x); o.h[1] = f2b(a.y); o.h[2] = f2b(a.z); o.h[3] = f2b(a.w);
    o.h[4] = f2b(b.x); o.h[5] = f2b(b.y); o.h[6] = f2b(b.z); o.h[7] = f2b(b.w);
    *(uint4*)(out + i) = o.u;
}

__global__ void init_h(unsigned short* __restrict__ hbuf) {
    size_t i = ((size_t)blockIdx.x * blockDim.x + threadIdx.x) * 8;
    uint4 z = {0, 0, 0, 0};
    *(uint4*)(hbuf + i) = z;
}

__launch_bounds__(512, 1)
__global__ void lstm_core(const unsigned short* __restrict__ xb,
                          const unsigned short* __restrict__ Wr,
                          const float* __restrict__ bias_r,
                          unsigned short* __restrict__ hbuf,
                          const unsigned short* __restrict__ Vw,
                          const float* __restrict__ Vbias,
                          float* __restrict__ out) {
    cg::grid_group grid = cg::this_grid();
    __shared__ float gxp[8][64][20];   // [wave][row][col padded] — stride 20 => 2-way banks, 16B-aligned rows

    const int bid  = blockIdx.x;       // 256 blocks, each owns 16 gate-cols (4 h-cols)
    const int tid  = threadIdx.x;      // 512 threads, 8 waves
    const int wave = tid >> 6;
    const int lane = tid & 63;
    const int lrow = lane & 15;
    const int kq   = (lane >> 4) << 3; // 0,8,16,24
    const int n0   = bid << 4;

    // cell-update mapping (first 256 threads)
    const int ob   = tid >> 2;
    const int lhc  = tid & 3;
    const int hcol = (bid << 2) + lhc;
    const float4 bb = *(const float4*)&bias_r[n0 + (lhc << 2)];

    // weight pointer: wave's K-slice (256 of 2048), fixed across steps
    const unsigned short* wptr = Wr + (size_t)(n0 + lrow) * KD + (wave << 8) + kq;

    // A-row pointers: waves 0-3 read x (k 0..1023), waves 4-7 read h (k 0..1023)
    const bool isx = wave < 4;
    const unsigned short* arow[4];
    if (isx) {
        int ko = (wave << 8) + kq;
        #pragma unroll
        for (int m = 0; m < 4; ++m)
            arow[m] = xb + (size_t)(m * 16 + lrow) * (TSTEPS * ID) + ko;
    } else {
        int ko = ((wave - 4) << 8) + kq;
        #pragma unroll
        for (int m = 0; m < 4; ++m)
            arow[m] = hbuf + (size_t)(m * 16 + lrow) * HD + ko;
    }

    float c_reg = 0.f;
    float hlast = 0.f;
    const int qr = (lane >> 4) << 2;

    for (int t = 0; t < TSTEPS; ++t) {
        const int cur = t & 1;
        f32x4 acc0 = {0,0,0,0}, acc1 = {0,0,0,0}, acc2 = {0,0,0,0}, acc3 = {0,0,0,0};
        const size_t aoff = isx ? (size_t)t * ID : (size_t)cur * (NB * HD);
        const unsigned short* a0 = arow[0] + aoff;
        const unsigned short* a1 = arow[1] + aoff;
        const unsigned short* a2 = arow[2] + aoff;
        const unsigned short* a3 = arow[3] + aoff;
        #pragma unroll 4
        for (int kk = 0; kk < 256; kk += 32) {
            bf16x8 bfrag = *(const bf16x8*)(wptr + kk);
            acc0 = __builtin_amdgcn_mfma_f32_16x16x32_bf16(*(const bf16x8*)(a0 + kk), bfrag, acc0, 0, 0, 0);
            acc1 = __builtin_amdgcn_mfma_f32_16x16x32_bf16(*(const bf16x8*)(a1 + kk), bfrag, acc1, 0, 0, 0);
            acc2 = __builtin_amdgcn_mfma_f32_16x16x32_bf16(*(const bf16x8*)(a2 + kk), bfrag, acc2, 0, 0, 0);
            acc3 = __builtin_amdgcn_mfma_f32_16x16x32_bf16(*(const bf16x8*)(a3 + kk), bfrag, acc3, 0, 0, 0);
        }
        #pragma unroll
        for (int r = 0; r < 4; ++r) gxp[wave][ 0 + qr + r][lrow] = acc0[r];
        #pragma unroll
        for (int r = 0; r < 4; ++r) gxp[wave][16 + qr + r][lrow] = acc1[r];
        #pragma unroll
        for (int r = 0; r < 4; ++r) gxp[wave][32 + qr + r][lrow] = acc2[r];
        #pragma unroll
        for (int r = 0; r < 4; ++r) gxp[wave][48 + qr + r][lrow] = acc3[r];
        __syncthreads();
        if (tid < 256) {
            float fpre = bb.x, ipre = bb.y, opre = bb.z, gpre = bb.w;
            #pragma unroll
            for (int w = 0; w < 8; ++w) {
                float4 s = *(const float4*)&gxp[w][ob][lhc << 2];
                fpre += s.x; ipre += s.y; opre += s.z; gpre += s.w;
            }
            float fg = 1.0f / (1.0f + __expf(-fpre));
            float ig = 1.0f / (1.0f + __expf(-ipre));
            float og = 1.0f / (1.0f + __expf(-opre));
            float gg = tanhf(gpre);
            c_reg = fg * c_reg + ig * gg;
            float hh = og * tanhf(c_reg);
            hbuf[(size_t)(cur ^ 1) * (NB * HD) + (size_t)ob * HD + hcol] = f2b(hh);
            if (t == TSTEPS - 1) hlast = hh;
        }
        grid.sync();
    }

    if (tid < 256) {
        out[(size_t)ob * HD + hcol] = c_reg;                    // c
        out[65536 + (size_t)ob * HD + hcol] = hlast;            // h
    }

    // final projection: last_out = h @ V^T + V_b, blocks 0..63 (N=1024)
    if (bid < 64) {
        f32x4 acc0 = {0,0,0,0}, acc1 = {0,0,0,0}, acc2 = {0,0,0,0}, acc3 = {0,0,0,0};
        const int ko = (wave << 7) + kq;                        // K=1024 split 8 x 128
        const unsigned short* vp = Vw + (size_t)(n0 + lrow) * HD + ko;
        const unsigned short* h0 = hbuf + (size_t)lrow * HD + ko;   // final h in buffer 0
        #pragma unroll
        for (int kk = 0; kk < 128; kk += 32) {
            bf16x8 bfrag = *(const bf16x8*)(vp + kk);
            acc0 = __builtin_amdgcn_mfma_f32_16x16x32_bf16(*(const bf16x8*)(h0 + kk),                 bfrag, acc0, 0, 0, 0);
            acc1 = __builtin_amdgcn_mfma_f32_16x16x32_bf16(*(const bf16x8*)(h0 + 16 * HD + kk),       bfrag, acc1, 0, 0, 0);
            acc2 = __builtin_amdgcn_mfma_f32_16x16x32_bf16(*(const bf16x8*)(h0 + 32 * HD + kk),       bfrag, acc2, 0, 0, 0);
            acc3 = __builtin_amdgcn_mfma_f32_16x16x32_bf16(*(const bf16x8*)(h0 + 48 * HD + kk),       bfrag, acc3, 0, 0, 0);
        }
        #pragma unroll
        for (int r = 0; r < 4; ++r) gxp[wave][ 0 + qr + r][lrow] = acc0[r];
        #pragma unroll
        for (int r = 0; r < 4; ++r) gxp[wave][16 + qr + r][lrow] = acc1[r];
        #pragma unroll
        for (int r = 0; r < 4; ++r) gxp[wave][32 + qr + r][lrow] = acc2[r];
        #pragma unroll
        for (int r = 0; r < 4; ++r) gxp[wave][48 + qr + r][lrow] = acc3[r];
        __syncthreads();
        if (tid < 256) {
            float4 vb = *(const float4*)&Vbias[n0 + (lhc << 2)];
            float4 res = vb;
            #pragma unroll
            for (int w = 0; w < 8; ++w) {
                float4 s = *(const float4*)&gxp[w][ob][lhc << 2];
                res.x += s.x; res.y += s.y; res.z += s.z; res.w += s.w;
            }
            *(float4*)&out[131072 + (size_t)ob * 1024 + n0 + (lhc << 2)] = res;
        }
    }
}

extern "C" void kernel_launch(void* const* d_in, const int* in_sizes, int n_in,
                              void* d_out, int out_size, void* d_ws, size_t ws_size,
                              hipStream_t stream) {
    const float* x   = (const float*)d_in[0];
    const float* Wf  = (const float*)d_in[1];
    const float* bf_ = (const float*)d_in[2];
    const float* Wi  = (const float*)d_in[3];
    const float* bi_ = (const float*)d_in[4];
    const float* Wc  = (const float*)d_in[5];
    const float* bc_ = (const float*)d_in[6];
    const float* Wo  = (const float*)d_in[7];
    const float* bo_ = (const float*)d_in[8];
    const float* Vw  = (const float*)d_in[9];
    const float* Vb  = (const float*)d_in[10];

    char* ws = (char*)d_ws;
    unsigned short* xb     = (unsigned short*)(ws + XOFF);
    unsigned short* Wr     = (unsigned short*)(ws + WOFF);
    unsigned short* Vbf    = (unsigned short*)(ws + VOFF);
    float*          bias_r = (float*)(ws + BOFF);
    unsigned short* hbuf   = (unsigned short*)(ws + HOFF);
    float*          outp   = (float*)d_out;

    cvt_x <<<8192, 256, 0, stream>>>(x, xb);
    cvt_w <<<4096, 256, 0, stream>>>(Wf, Wi, Wo, Wc, bf_, bi_, bo_, bc_, Wr, bias_r);
    cvt_v <<<512, 256, 0, stream>>>(Vw, Vbf);
    init_h<<<32, 256, 0, stream>>>(hbuf);

    void* args[] = {&xb, &Wr, &bias_r, &hbuf, &Vbf, &Vb, &outp};
    hipLaunchCooperativeKernel((const void*)lstm_core, dim3(256), dim3(512), args, 0, stream);
}

// Round 2
// 3069.416 us; speedup vs baseline: 3.3389x; 3.3389x over previous
//
#include <hip/hip_runtime.h>
#include <hip/hip_bf16.h>
#include <hip/hip_cooperative_groups.h>

namespace cg = cooperative_groups;

typedef __bf16 bf16x8 __attribute__((ext_vector_type(8)));
typedef float f32x4 __attribute__((ext_vector_type(4)));

#define TSTEPS 256
#define NB 64
#define ID 1024
#define HD 1024
#define KD 2048
#define NGATE 4096

// ws layout (bytes)
#define XOFF 0ull
#define WOFF 33554432ull
#define VOFF 50331648ull
#define BOFF 52428800ull
#define HOFF 52445184ull
#define BAROFF 52707328ull   // HOFF + 2*64*1024*2

__device__ __forceinline__ unsigned short f2b(float f) {
    unsigned int u = __float_as_uint(f);
    unsigned int r = (u + 0x7fffu + ((u >> 16) & 1u)) >> 16;
    return (unsigned short)r;
}

__device__ __forceinline__ bf16x8 as_bf16x8(uint4 u) {
    union { uint4 u; bf16x8 b; } c; c.u = u; return c.b;
}

// ---- coherent (L1/L2-bypass, L3 coherence point) access helpers ----
__device__ __forceinline__ uint4 ld_b128_bypass(const unsigned short* p) {
    uint4 r;
    asm volatile("global_load_dwordx4 %0, %1, off sc0 sc1" : "=v"(r) : "v"(p));
    return r;
}
__device__ __forceinline__ unsigned int ld_dw_bypass(const unsigned int* p) {
    unsigned int r;
    asm volatile("global_load_dword %0, %1, off sc0 sc1\n\ts_waitcnt vmcnt(0)"
                 : "=v"(r) : "v"(p) : "memory");
    return r;
}
__device__ __forceinline__ void st_dw_bypass(unsigned int* p, unsigned int v) {
    asm volatile("global_store_dword %0, %1, off sc0 sc1\n\ts_waitcnt vmcnt(0)"
                 :: "v"(p), "v"(v) : "memory");
}
__device__ __forceinline__ void st_short_bypass(unsigned short* p, unsigned short v) {
    asm volatile("global_store_short %0, %1, off sc0 sc1"
                 :: "v"(p), "v"((unsigned int)v) : "memory");
}

__global__ void cvt_x(const float* __restrict__ in, unsigned short* __restrict__ out) {
    size_t i = ((size_t)blockIdx.x * blockDim.x + threadIdx.x) * 8;
    float4 a = *(const float4*)(in + i);
    float4 b = *(const float4*)(in + i + 4);
    union { unsigned short h[8]; uint4 u; } o;
    o.h[0] = f2b(a.x); o.h[1] = f2b(a.y); o.h[2] = f2b(a.z); o.h[3] = f2b(a.w);
    o.h[4] = f2b(b.x); o.h[5] = f2b(b.y); o.h[6] = f2b(b.z); o.h[7] = f2b(b.w);
    *(uint4*)(out + i) = o.u;
}

__global__ void cvt_w(const float* __restrict__ Wf, const float* __restrict__ Wi,
                      const float* __restrict__ Wo, const float* __restrict__ Wc,
                      const float* __restrict__ bf_, const float* __restrict__ bi_,
                      const float* __restrict__ bo_, const float* __restrict__ bc_,
                      unsigned short* __restrict__ Wr, float* __restrict__ bias_r) {
    int idx = blockIdx.x * 256 + threadIdx.x;   // 4096*256 total
    int np = idx >> 8;            // n' = hcol*4 + gate
    int k  = (idx & 255) * 8;
    int g = np & 3, h = np >> 2;
    const float* W = (g == 0) ? Wf : (g == 1) ? Wi : (g == 2) ? Wo : Wc;
    const float* src = W + (size_t)h * KD + k;
    float4 a = *(const float4*)src;
    float4 b = *(const float4*)(src + 4);
    union { unsigned short h[8]; uint4 u; } o;
    o.h[0] = f2b(a.x); o.h[1] = f2b(a.y); o.h[2] = f2b(a.z); o.h[3] = f2b(a.w);
    o.h[4] = f2b(b.x); o.h[5] = f2b(b.y); o.h[6] = f2b(b.z); o.h[7] = f2b(b.w);
    *(uint4*)(Wr + (size_t)np * KD + k) = o.u;
    if (k == 0) {
        const float* B = (g == 0) ? bf_ : (g == 1) ? bi_ : (g == 2) ? bo_ : bc_;
        bias_r[np] = B[h];
    }
}

__global__ void cvt_v(const float* __restrict__ V, unsigned short* __restrict__ out) {
    size_t i = ((size_t)blockIdx.x * blockDim.x + threadIdx.x) * 8;
    float4 a = *(const float4*)(V + i);
    float4 b = *(const float4*)(V + i + 4);
    union { unsigned short h[8]; uint4 u; } o;
    o.h[0] = f2b(a.x); o.h[1] = f2b(a.y); o.h[2] = f2b(a.z); o.h[3] = f2b(a.w);
    o.h[4] = f2b(b.x); o.h[5] = f2b(b.y); o.h[6] = f2b(b.z); o.h[7] = f2b(b.w);
    *(uint4*)(out + i) = o.u;
}

__global__ void init_h(unsigned short* __restrict__ hbuf) {
    size_t i = ((size_t)blockIdx.x * blockDim.x + threadIdx.x) * 8;
    uint4 z = {0, 0, 0, 0};
    *(uint4*)(hbuf + i) = z;
}

__global__ void init_bar(unsigned int* __restrict__ bar) {
    bar[blockIdx.x * 256 + threadIdx.x] = 0;
}

__launch_bounds__(512, 2)
__global__ void lstm_core(const unsigned short* __restrict__ xb,
                          const unsigned short* __restrict__ Wr,
                          const float* __restrict__ bias_r,
                          unsigned short* __restrict__ hbuf,
                          const unsigned short* __restrict__ Vw,
                          const float* __restrict__ Vbias,
                          float* __restrict__ out,
                          unsigned int* __restrict__ bar) {
    __shared__ float gxp[8][64][20];

    const int bid  = blockIdx.x;       // 256 blocks, each owns 16 gate-cols (4 h-cols)
    const int tid  = threadIdx.x;      // 512 threads, 8 waves
    const int wave = tid >> 6;
    const int lane = tid & 63;
    const int lrow = lane & 15;
    const int kq   = (lane >> 4) << 3; // 0,8,16,24
    const int n0   = bid << 4;

    unsigned int* slots = bar;         // 256 dwords
    unsigned int* go    = bar + 512;   // own cacheline

    // cell-update mapping (first 256 threads)
    const int ob   = tid >> 2;
    const int lhc  = tid & 3;
    const int hcol = (bid << 2) + lhc;
    const float4 bb = *(const float4*)&bias_r[n0 + (lhc << 2)];

    // weight pointer: wave's K-slice (256 of 2048), fixed across steps
    const unsigned short* wptr = Wr + (size_t)(n0 + lrow) * KD + (wave << 8) + kq;

    // A-row pointers: waves 0-3 read x (k 0..1023), waves 4-7 read h (k 0..1023)
    const bool isx = wave < 4;
    const unsigned short* arow[4];
    if (isx) {
        int ko = (wave << 8) + kq;
        #pragma unroll
        for (int m = 0; m < 4; ++m)
            arow[m] = xb + (size_t)(m * 16 + lrow) * (TSTEPS * ID) + ko;
    } else {
        int ko = ((wave - 4) << 8) + kq;
        #pragma unroll
        for (int m = 0; m < 4; ++m)
            arow[m] = hbuf + (size_t)(m * 16 + lrow) * HD + ko;
    }

    float c_reg = 0.f;
    float hlast = 0.f;
    const int qr = (lane >> 4) << 2;

    for (int t = 0; t < TSTEPS; ++t) {
        const int cur = t & 1;
        f32x4 acc0 = {0,0,0,0}, acc1 = {0,0,0,0}, acc2 = {0,0,0,0}, acc3 = {0,0,0,0};

        if (isx) {
            const size_t aoff = (size_t)t * ID;
            const unsigned short* a0 = arow[0] + aoff;
            const unsigned short* a1 = arow[1] + aoff;
            const unsigned short* a2 = arow[2] + aoff;
            const unsigned short* a3 = arow[3] + aoff;
            #pragma unroll 4
            for (int kk = 0; kk < 256; kk += 32) {
                bf16x8 bfrag = *(const bf16x8*)(wptr + kk);
                acc0 = __builtin_amdgcn_mfma_f32_16x16x32_bf16(*(const bf16x8*)(a0 + kk), bfrag, acc0, 0, 0, 0);
                acc1 = __builtin_amdgcn_mfma_f32_16x16x32_bf16(*(const bf16x8*)(a1 + kk), bfrag, acc1, 0, 0, 0);
                acc2 = __builtin_amdgcn_mfma_f32_16x16x32_bf16(*(const bf16x8*)(a2 + kk), bfrag, acc2, 0, 0, 0);
                acc3 = __builtin_amdgcn_mfma_f32_16x16x32_bf16(*(const bf16x8*)(a3 + kk), bfrag, acc3, 0, 0, 0);
            }
        } else {
            const size_t aoff = (size_t)cur * (NB * HD);
            uint4 hr[4][8];
            #pragma unroll
            for (int m = 0; m < 4; ++m)
                #pragma unroll
                for (int j = 0; j < 8; ++j)
                    hr[m][j] = ld_b128_bypass(arow[m] + aoff + j * 32);
            asm volatile("s_waitcnt vmcnt(0)" ::: "memory");
            __builtin_amdgcn_sched_barrier(0);
            #pragma unroll
            for (int j = 0; j < 8; ++j) {
                bf16x8 bfrag = *(const bf16x8*)(wptr + j * 32);
                acc0 = __builtin_amdgcn_mfma_f32_16x16x32_bf16(as_bf16x8(hr[0][j]), bfrag, acc0, 0, 0, 0);
                acc1 = __builtin_amdgcn_mfma_f32_16x16x32_bf16(as_bf16x8(hr[1][j]), bfrag, acc1, 0, 0, 0);
                acc2 = __builtin_amdgcn_mfma_f32_16x16x32_bf16(as_bf16x8(hr[2][j]), bfrag, acc2, 0, 0, 0);
                acc3 = __builtin_amdgcn_mfma_f32_16x16x32_bf16(as_bf16x8(hr[3][j]), bfrag, acc3, 0, 0, 0);
            }
        }

        #pragma unroll
        for (int r = 0; r < 4; ++r) gxp[wave][ 0 + qr + r][lrow] = acc0[r];
        #pragma unroll
        for (int r = 0; r < 4; ++r) gxp[wave][16 + qr + r][lrow] = acc1[r];
        #pragma unroll
        for (int r = 0; r < 4; ++r) gxp[wave][32 + qr + r][lrow] = acc2[r];
        #pragma unroll
        for (int r = 0; r < 4; ++r) gxp[wave][48 + qr + r][lrow] = acc3[r];
        __syncthreads();

        if (tid < 256) {
            float fpre = bb.x, ipre = bb.y, opre = bb.z, gpre = bb.w;
            #pragma unroll
            for (int w = 0; w < 8; ++w) {
                float4 s = *(const float4*)&gxp[w][ob][lhc << 2];
                fpre += s.x; ipre += s.y; opre += s.z; gpre += s.w;
            }
            float fg = 1.0f / (1.0f + __expf(-fpre));
            float ig = 1.0f / (1.0f + __expf(-ipre));
            float og = 1.0f / (1.0f + __expf(-opre));
            float gg = tanhf(gpre);
            c_reg = fg * c_reg + ig * gg;
            float hh = og * tanhf(c_reg);
            st_short_bypass(hbuf + (size_t)(cur ^ 1) * (NB * HD) + (size_t)ob * HD + hcol, f2b(hh));
            asm volatile("s_waitcnt vmcnt(0)" ::: "memory");
            if (t == TSTEPS - 1) hlast = hh;
        }
        __syncthreads();   // all h-stores of this block are globally visible

        // ---- custom device-scope barrier (no L2 invalidation) ----
        if (tid == 0) st_dw_bypass(&slots[bid], (unsigned int)(t + 1));
        if (bid == 0) {
            if (tid < 256) {
                while (ld_dw_bypass(&slots[tid]) < (unsigned int)(t + 1))
                    __builtin_amdgcn_s_sleep(1);
            }
            __syncthreads();
            if (tid == 0) st_dw_bypass(go, (unsigned int)(t + 1));
        }
        if (tid == 0) {
            while (ld_dw_bypass(go) < (unsigned int)(t + 1))
                __builtin_amdgcn_s_sleep(1);
        }
        __syncthreads();
    }

    if (tid < 256) {
        out[(size_t)ob * HD + hcol] = c_reg;                    // c
        out[65536 + (size_t)ob * HD + hcol] = hlast;            // h
    }

    // final projection: last_out = h @ V^T + V_b, blocks 0..63 (N=1024)
    if (bid < 64) {
        f32x4 acc0 = {0,0,0,0}, acc1 = {0,0,0,0}, acc2 = {0,0,0,0}, acc3 = {0,0,0,0};
        const int ko = (wave << 7) + kq;                        // K=1024 split 8 x 128
        const unsigned short* vp = Vw + (size_t)(n0 + lrow) * HD + ko;
        const unsigned short* h0 = hbuf + (size_t)lrow * HD + ko;   // final h in buffer 0
        uint4 pr[4][4];
        #pragma unroll
        for (int m = 0; m < 4; ++m)
            #pragma unroll
            for (int j = 0; j < 4; ++j)
                pr[m][j] = ld_b128_bypass(h0 + (size_t)m * 16 * HD + j * 32);
        asm volatile("s_waitcnt vmcnt(0)" ::: "memory");
        __builtin_amdgcn_sched_barrier(0);
        #pragma unroll
        for (int j = 0; j < 4; ++j) {
            bf16x8 bfrag = *(const bf16x8*)(vp + j * 32);
            acc0 = __builtin_amdgcn_mfma_f32_16x16x32_bf16(as_bf16x8(pr[0][j]), bfrag, acc0, 0, 0, 0);
            acc1 = __builtin_amdgcn_mfma_f32_16x16x32_bf16(as_bf16x8(pr[1][j]), bfrag, acc1, 0, 0, 0);
            acc2 = __builtin_amdgcn_mfma_f32_16x16x32_bf16(as_bf16x8(pr[2][j]), bfrag, acc2, 0, 0, 0);
            acc3 = __builtin_amdgcn_mfma_f32_16x16x32_bf16(as_bf16x8(pr[3][j]), bfrag, acc3, 0, 0, 0);
        }
        #pragma unroll
        for (int r = 0; r < 4; ++r) gxp[wave][ 0 + qr + r][lrow] = acc0[r];
        #pragma unroll
        for (int r = 0; r < 4; ++r) gxp[wave][16 + qr + r][lrow] = acc1[r];
        #pragma unroll
        for (int r = 0; r < 4; ++r) gxp[wave][32 + qr + r][lrow] = acc2[r];
        #pragma unroll
        for (int r = 0; r < 4; ++r) gxp[wave][48 + qr + r][lrow] = acc3[r];
        __syncthreads();
        if (tid < 256) {
            float4 vb = *(const float4*)&Vbias[n0 + (lhc << 2)];
            float4 res = vb;
            #pragma unroll
            for (int w = 0; w < 8; ++w) {
                float4 s = *(const float4*)&gxp[w][ob][lhc << 2];
                res.x += s.x; res.y += s.y; res.z += s.z; res.w += s.w;
            }
            *(float4*)&out[131072 + (size_t)ob * 1024 + n0 + (lhc << 2)] = res;
        }
    }
}

extern "C" void kernel_launch(void* const* d_in, const int* in_sizes, int n_in,
                              void* d_out, int out_size, void* d_ws, size_t ws_size,
                              hipStream_t stream) {
    const float* x   = (const float*)d_in[0];
    const float* Wf  = (const float*)d_in[1];
    const float* bf_ = (const float*)d_in[2];
    const float* Wi  = (const float*)d_in[3];
    const float* bi_ = (const float*)d_in[4];
    const float* Wc  = (const float*)d_in[5];
    const float* bc_ = (const float*)d_in[6];
    const float* Wo  = (const float*)d_in[7];
    const float* bo_ = (const float*)d_in[8];
    const float* Vw  = (const float*)d_in[9];
    const float* Vb  = (const float*)d_in[10];

    char* ws = (char*)d_ws;
    unsigned short* xb     = (unsigned short*)(ws + XOFF);
    unsigned short* Wr     = (unsigned short*)(ws + WOFF);
    unsigned short* Vbf    = (unsigned short*)(ws + VOFF);
    float*          bias_r = (float*)(ws + BOFF);
    unsigned short* hbuf   = (unsigned short*)(ws + HOFF);
    unsigned int*   bar    = (unsigned int*)(ws + BAROFF);
    float*          outp   = (float*)d_out;

    cvt_x <<<8192, 256, 0, stream>>>(x, xb);
    cvt_w <<<4096, 256, 0, stream>>>(Wf, Wi, Wo, Wc, bf_, bi_, bo_, bc_, Wr, bias_r);
    cvt_v <<<512, 256, 0, stream>>>(Vw, Vbf);
    init_h<<<32, 256, 0, stream>>>(hbuf);
    init_bar<<<4, 256, 0, stream>>>(bar);

    void* args[] = {&xb, &Wr, &bias_r, &hbuf, &Vbf, &Vb, &outp, &bar};
    hipLaunchCooperativeKernel((const void*)lstm_core, dim3(256), dim3(512), args, 0, stream);
}